// Round 12
// baseline (260.996 us; speedup 1.0000x reference)
//
#include <hip/hip_runtime.h>
#include <hip/hip_bf16.h>

#define DEV static __device__ __forceinline__

typedef __bf16 bf16x8 __attribute__((ext_vector_type(8)));
typedef float f32x4 __attribute__((ext_vector_type(4)));
typedef float f32x16 __attribute__((ext_vector_type(16)));
typedef unsigned u32x4 __attribute__((ext_vector_type(4)));
typedef unsigned short u16x8 __attribute__((ext_vector_type(8)));
typedef unsigned short u16x4 __attribute__((ext_vector_type(4)));

DEV unsigned short f2bf(float f) {
  unsigned u = __builtin_bit_cast(unsigned, f);
  u += 0x7fffu + ((u >> 16) & 1u);
  return (unsigned short)(u >> 16);
}
DEV float bf2f(unsigned short s) {
  return __builtin_bit_cast(float, (unsigned)s << 16);
}
DEV f32x4 mfma16(bf16x8 a, bf16x8 b, f32x4 c) {
  return __builtin_amdgcn_mfma_f32_16x16x32_bf16(a, b, c, 0, 0, 0);
}
DEV f32x16 mfma32(bf16x8 a, bf16x8 b, f32x16 c) {
  return __builtin_amdgcn_mfma_f32_32x32x16_bf16(a, b, c, 0, 0, 0);
}
DEV bf16x8 ld8(const unsigned short* p) {
  return __builtin_bit_cast(bf16x8, *(const u16x8*)p);
}
// async global->LDS, 16B per lane; LDS dest wave-uniform base + lane*16
DEV void gload16(const unsigned short* g, unsigned short* l) {
  auto* g1 = reinterpret_cast<const __attribute__((address_space(1))) unsigned int*>(
      reinterpret_cast<uintptr_t>(g));
  auto* l3 = reinterpret_cast<__attribute__((address_space(3))) unsigned int*>(
      reinterpret_cast<uintptr_t>(l));
  __builtin_amdgcn_global_load_lds(g1, l3, 16, 0, 0);
}

// ---------------- fused prep, single fmap pass, float4 global reads (unchanged) -----
__global__ __launch_bounds__(256) void prep_k(const float* __restrict__ fmap,
                                              const float* __restrict__ gamma,
                                              const float* __restrict__ wq,
                                              const float* __restrict__ wv,
                                              const float* __restrict__ wo,
                                              unsigned short* __restrict__ xt,
                                              unsigned short* __restrict__ wqb,
                                              unsigned short* __restrict__ wvb,
                                              unsigned short* __restrict__ wob) {
  int bid = blockIdx.x, tid = threadIdx.x;
  if (bid >= 256) {
    int t4 = bid - 256;            // 0..95, 32 blocks per tensor
    int g = t4 >> 5;
    const float* src = (g == 0) ? wq : (g == 1) ? wv : wo;
    unsigned short* dst = (g == 0) ? wqb : (g == 1) ? wvb : wob;
    int base = (t4 & 31) * 1024 + tid;
    const float4* s = (const float4*)src;
#pragma unroll
    for (int i = 0; i < 4; ++i) {
      int idx = base + i * 256;
      float4 a = s[idx * 2], b = s[idx * 2 + 1];
      u16x8 o;
      o[0] = f2bf(a.x); o[1] = f2bf(a.y); o[2] = f2bf(a.z); o[3] = f2bf(a.w);
      o[4] = f2bf(b.x); o[5] = f2bf(b.y); o[6] = f2bf(b.z); o[7] = f2bf(b.w);
      ((u16x8*)dst)[idx] = o;
    }
    return;
  }
  __shared__ float slab[512][33];   // [c][n_local], +1 pad
  __shared__ float psum[32][33];    // [cg][n] partial sums, +1 pad
  __shared__ float rn_l[32];
  __shared__ float gl[512];
  int b = bid >> 5, n0 = (bid & 31) * 32;
  gl[tid] = gamma[tid];
  gl[tid + 256] = gamma[tid + 256];
  // phase 1: float4 loads along n; 16 channels per thread
  int q = tid & 7, cg = tid >> 3;
  int n4 = q * 4;
  float s0 = 0.f, s1 = 0.f, s2 = 0.f, s3 = 0.f;
  const float* pb = fmap + ((size_t)(b * 512 + cg * 16)) * 1024 + n0 + n4;
#pragma unroll
  for (int i = 0; i < 16; ++i) {
    float4 v = *(const float4*)(pb + (size_t)i * 1024);
    int c = cg * 16 + i;
    slab[c][n4] = v.x; slab[c][n4 + 1] = v.y; slab[c][n4 + 2] = v.z; slab[c][n4 + 3] = v.w;
    s0 += v.x * v.x; s1 += v.y * v.y; s2 += v.z * v.z; s3 += v.w * v.w;
  }
  psum[cg][n4] = s0; psum[cg][n4 + 1] = s1; psum[cg][n4 + 2] = s2; psum[cg][n4 + 3] = s3;
  __syncthreads();
  if (tid < 32) {
    float ts = 0.f;
#pragma unroll
    for (int k = 0; k < 32; ++k) ts += psum[k][tid];
    rn_l[tid] = 22.62741699796952f / fmaxf(sqrtf(ts), 1e-12f);
  }
  __syncthreads();
  // phase 2: normalize + transpose from LDS, 16B stores
  int nn = tid >> 3, cc = tid & 7;
  float sc = rn_l[nn];
#pragma unroll
  for (int c0 = 0; c0 < 512; c0 += 64) {
    u16x8 o;
#pragma unroll
    for (int e = 0; e < 8; ++e) {
      int c = c0 + cc * 8 + e;
      o[e] = f2bf(slab[c][nn] * sc * gl[c]);
    }
    *(u16x8*)(xt + ((size_t)(b * 1024 + n0 + nn)) * 512 + c0 + cc * 8) = o;
  }
}

// ---------------- fused q+v GEMM, double-buffered 2-phase prefetch (unchanged) ------
__global__ __launch_bounds__(512) void gemm_qv_k(const unsigned short* __restrict__ A,
                                                 const unsigned short* __restrict__ wqb,
                                                 const unsigned short* __restrict__ wvb,
                                                 const float* __restrict__ nkv,
                                                 unsigned short* __restrict__ QF,
                                                 unsigned short* __restrict__ VF,
                                                 float* __restrict__ qsqs,
                                                 float* __restrict__ p0g) {
  __shared__ unsigned short a_lds[2][128 * 64];
  __shared__ unsigned short bq_lds[2][128 * 64];
  __shared__ unsigned short bv_lds[2][128 * 64];   // 96 KB total
  int tid = threadIdx.x, lane = tid & 63, wid = tid >> 6;
  int isV = wid >> 2, gw = wid & 3;
  int wr = gw >> 1, wc = gw & 1;
  int m0 = blockIdx.y * 128, n0 = blockIdx.x * 128;
  int srow = (lane >> 3);
  int scol = ((lane & 7) ^ ((lane >> 3) & 7)) * 8;
  f32x4 acc[4][4] = {};

#define QV_STAGE(BUF, KT)                                                          \
  {                                                                                \
    int il0 = wid * 2;                                                             \
    _Pragma("unroll")                                                              \
    for (int i = 0; i < 2; ++i) {                                                  \
      int il = il0 + i;                                                            \
      gload16(A + (size_t)(m0 + il * 8 + srow) * 512 + (KT) + scol, &a_lds[BUF][il * 512]);   \
      gload16(wqb + (size_t)(n0 + il * 8 + srow) * 512 + (KT) + scol, &bq_lds[BUF][il * 512]); \
      gload16(wvb + (size_t)(n0 + il * 8 + srow) * 512 + (KT) + scol, &bv_lds[BUF][il * 512]); \
    }                                                                              \
  }

  QV_STAGE(0, 0)
  asm volatile("s_waitcnt vmcnt(0)" ::: "memory");
  __syncthreads();
  int cur = 0;
#pragma unroll 1
  for (int t = 0; t < 8; ++t) {
    if (t < 7) QV_STAGE(cur ^ 1, (t + 1) * 64)
    const unsigned short* al = &a_lds[cur][0];
    const unsigned short* bl = isV ? &bv_lds[cur][0] : &bq_lds[cur][0];
#pragma unroll
    for (int ks = 0; ks < 2; ++ks) {
      int c = ks * 4 + (lane >> 4);
      int cs = (c ^ (lane & 7)) * 8;
      bf16x8 af[4], bfr[4];
#pragma unroll
      for (int rt = 0; rt < 4; ++rt)
        af[rt] = ld8(&al[(wr * 64 + rt * 16 + (lane & 15)) * 64 + cs]);
#pragma unroll
      for (int ct = 0; ct < 4; ++ct)
        bfr[ct] = ld8(&bl[(wc * 64 + ct * 16 + (lane & 15)) * 64 + cs]);
#pragma unroll
      for (int rt = 0; rt < 4; ++rt)
#pragma unroll
        for (int ct = 0; ct < 4; ++ct)
          acc[rt][ct] = mfma16(af[rt], bfr[ct], acc[rt][ct]);
    }
    asm volatile("s_waitcnt vmcnt(0)" ::: "memory");
    __syncthreads();
    cur ^= 1;
  }
  if (!isV) {
    const float COEF = 0.18033688011112042f;  // 0.125 * log2(e)
    int head = blockIdx.x * 2 + wc;
    const float* nk = nkv + head * 64;
    float nk_own[4], nks = 0.f;
#pragma unroll
    for (int ct = 0; ct < 4; ++ct) {
      nk_own[ct] = nk[ct * 16 + (lane & 15)];
      nks += nk_own[ct] * nk_own[ct];
    }
    nks += __shfl_xor(nks, 1); nks += __shfl_xor(nks, 2);
    nks += __shfl_xor(nks, 4); nks += __shfl_xor(nks, 8);
#pragma unroll
    for (int rt = 0; rt < 4; ++rt)
#pragma unroll
      for (int r = 0; r < 4; ++r) {
        float qs = 0.f, dot = 0.f;
        unsigned short qr[4];
#pragma unroll
        for (int ct = 0; ct < 4; ++ct) {
          unsigned short us = f2bf(acc[rt][ct][r]);
          qr[ct] = us;
          float v = bf2f(us);
          qs += v * v;
          dot += v * nk_own[ct];
        }
        int n = m0 + wr * 64 + rt * 16 + (lane >> 4) * 4 + r;
        int bb = n >> 10, nl = n & 1023;
        int bh = bb * 8 + head;
        size_t fidx = (size_t)(bh * 32 + (nl >> 5)) * 2048 + (nl & 31) * 16 + (lane & 15);
#pragma unroll
        for (int ct = 0; ct < 4; ++ct) QF[fidx + ct * 512] = qr[ct];
        qs += __shfl_xor(qs, 1); qs += __shfl_xor(qs, 2);
        qs += __shfl_xor(qs, 4); qs += __shfl_xor(qs, 8);
        dot += __shfl_xor(dot, 1); dot += __shfl_xor(dot, 2);
        dot += __shfl_xor(dot, 4); dot += __shfl_xor(dot, 8);
        if ((lane & 15) == 0) {
          qsqs[bh * 1024 + nl] = qs * COEF;
          p0g[bh * 1024 + nl] = __builtin_amdgcn_exp2f((2.f * dot - nks) * COEF);
        }
      }
  } else {
#pragma unroll
    for (int rt = 0; rt < 4; ++rt)
#pragma unroll
      for (int ct = 0; ct < 4; ++ct) {
        int nb = m0 + wr * 64 + rt * 16 + (lane >> 4) * 4;
        int o = n0 + wc * 64 + ct * 16 + (lane & 15);
        int b = nb >> 10, j = nb & 1023;
        int h = o >> 6, d = o & 63;
        int bh = b * 8 + h;
        size_t idx = (size_t)(bh * 32 + (j >> 5)) * 2048 + ((j >> 4) & 1) * 1024 + (d >> 5) * 512 +
                     (d & 31) * 16 + (j & 15);
        u16x4 pk;
#pragma unroll
        for (int r = 0; r < 4; ++r) pk[r] = f2bf(acc[rt][ct][r]);
        *(u16x4*)(VF + idx) = pk;
      }
  }
}

// ---------------- out-projection GEMM: 64x128x512, dbuf 2-phase prefetch (unchanged) --
__global__ __launch_bounds__(256) void gemm_o_k(const unsigned short* __restrict__ A,
                                                const unsigned short* __restrict__ Bt,
                                                float* __restrict__ Cp) {
  __shared__ unsigned short a_lds[2][64 * 64];
  __shared__ unsigned short b_lds[2][128 * 64];   // 48 KB
  int bid = blockIdx.x;
  int y = (bid >> 3) & 7;
  int x = (bid & 7) + ((bid >> 6) << 3);
  int m0 = y * 64, n0 = x * 128;
  int tid = threadIdx.x, lane = tid & 63, wid = tid >> 6;
  int wr = wid >> 1, wc = wid & 1;
  int srow = (lane >> 3);
  int scol = ((lane & 7) ^ ((lane >> 3) & 7)) * 8;
  f32x4 acc[2][4] = {};

#define O_STAGE(BUF, KT)                                                           \
  {                                                                                \
    _Pragma("unroll")                                                              \
    for (int i = 0; i < 2; ++i) {                                                  \
      int il = wid * 2 + i;                                                        \
      gload16(A + (size_t)(m0 + il * 8 + srow) * 512 + (KT) + scol, &a_lds[BUF][il * 512]);    \
    }                                                                              \
    _Pragma("unroll")                                                              \
    for (int i = 0; i < 4; ++i) {                                                  \
      int il = wid * 4 + i;                                                        \
      gload16(Bt + (size_t)(n0 + il * 8 + srow) * 512 + (KT) + scol, &b_lds[BUF][il * 512]);   \
    }                                                                              \
  }

  O_STAGE(0, 0)
  asm volatile("s_waitcnt vmcnt(0)" ::: "memory");
  __syncthreads();
  int cur = 0;
#pragma unroll 1
  for (int t = 0; t < 8; ++t) {
    if (t < 7) O_STAGE(cur ^ 1, (t + 1) * 64)
    const unsigned short* al = &a_lds[cur][0];
    const unsigned short* bl = &b_lds[cur][0];
#pragma unroll
    for (int ks = 0; ks < 2; ++ks) {
      int c = ks * 4 + (lane >> 4);
      int cs = (c ^ (lane & 7)) * 8;
      bf16x8 af[2], bfr[4];
#pragma unroll
      for (int rt = 0; rt < 2; ++rt)
        af[rt] = ld8(&al[(wr * 32 + rt * 16 + (lane & 15)) * 64 + cs]);
#pragma unroll
      for (int ct = 0; ct < 4; ++ct)
        bfr[ct] = ld8(&bl[(wc * 64 + ct * 16 + (lane & 15)) * 64 + cs]);
#pragma unroll
      for (int rt = 0; rt < 2; ++rt)
#pragma unroll
        for (int ct = 0; ct < 4; ++ct)
          acc[rt][ct] = mfma16(af[rt], bfr[ct], acc[rt][ct]);
    }
    asm volatile("s_waitcnt vmcnt(0)" ::: "memory");
    __syncthreads();
    cur ^= 1;
  }
  int bb = n0 >> 10;
#pragma unroll
  for (int rt = 0; rt < 2; ++rt)
#pragma unroll
    for (int ct = 0; ct < 4; ++ct)
#pragma unroll
      for (int r = 0; r < 4; ++r) {
        int row = m0 + wr * 32 + rt * 16 + (lane >> 4) * 4 + r;        // c
        int col = (n0 & 1023) + wc * 64 + ct * 16 + (lane & 15);       // n
        Cp[((size_t)(bb * 512 + row)) * 1024 + col] = acc[rt][ct][r];
      }
}

// ---------------- fused distance-attention, j-split, split QK chains ----------------
// R10 structure + __launch_bounds__(512,4): cap VGPR at 128 so 2 blocks/CU stay resident.
__global__ __launch_bounds__(512, 4) void attn_k(const unsigned short* __restrict__ QF,
                                                 const unsigned short* __restrict__ VF,
                                                 const float* __restrict__ qsqs,
                                                 const float* __restrict__ p0g,
                                                 const float* __restrict__ nkv,
                                                 unsigned short* __restrict__ att) {
  const float C2 = 0.36067376022224085f;  // 0.25 * log2(e)
  int bid = blockIdx.x;
  int s0 = bid >> 3;
  int bh = ((bid & 7) << 3) | (s0 & 7);
  int qt = s0 >> 3;
  int b = bh >> 3, h = bh & 7;
  int n0 = qt * 128;
  int tid = threadIdx.x, lane = tid & 63, wid = tid >> 6;
  int wq = wid & 3, jg = wid >> 2;
  int l31 = lane & 31, hi = lane >> 5;

  __shared__ float ob_l[32][4][64];
  __shared__ float dsb[4][32];
  __shared__ float p0_l[128];
  __shared__ float nv_l[64];
  __shared__ float dn_l[4][32];

  if (tid < 128) p0_l[tid] = p0g[bh * 1024 + n0 + tid];
  else if (tid < 192) nv_l[tid - 128] = nkv[512 + h * 64 + (tid - 128)];
  __syncthreads();

  bf16x8 qf[4];
  const unsigned short* qfp = QF + (size_t)(bh * 32 + qt * 4 + wq) * 2048 + l31 * 16 + hi * 8;
#pragma unroll
  for (int ks = 0; ks < 4; ++ks)
    qf[ks] = ld8(qfp + ks * 512);

  f32x16 oacc[2];
#pragma unroll
  for (int dh = 0; dh < 2; ++dh)
#pragma unroll
    for (int r = 0; r < 16; ++r) {
      int row = (r & 3) + 8 * (r >> 2) + 4 * hi;
      oacc[dh][r] = (jg == 0) ? p0_l[wq * 32 + row] * nv_l[dh * 32 + l31] : 0.f;
    }

  f32x4 dsum4 = {0.f, 0.f, 0.f, 0.f};
  const unsigned short* kbase = QF + (size_t)bh * 65536 + l31 * 16 + hi * 8;
  const unsigned short* vbase = VF + (size_t)bh * 65536 + l31 * 16 + hi * 8;
  const float* ksb = qsqs + bh * 1024 + 4 * hi;

  bf16x8 kfA[4], kfB[4], vfA[2][2], vfB[2][2];
  f32x4 ksqA[4], ksqB[4];

#define LOADT(S, JT)                                                        \
  {                                                                         \
    const unsigned short* kp_ = kbase + (JT) * 2048;                        \
    kf##S[0] = ld8(kp_);        kf##S[1] = ld8(kp_ + 512);                  \
    kf##S[2] = ld8(kp_ + 1024); kf##S[3] = ld8(kp_ + 1536);                 \
    const unsigned short* vp_ = vbase + (JT) * 2048;                        \
    vf##S[0][0] = ld8(vp_);        vf##S[0][1] = ld8(vp_ + 1024);           \
    vf##S[1][0] = ld8(vp_ + 512);  vf##S[1][1] = ld8(vp_ + 1536);           \
    const float* kq_ = ksb + (JT) * 32;                                     \
    ksq##S[0] = *(const f32x4*)(kq_);      ksq##S[1] = *(const f32x4*)(kq_ + 8);  \
    ksq##S[2] = *(const f32x4*)(kq_ + 16); ksq##S[3] = *(const f32x4*)(kq_ + 24); \
  }

#define COMPT(S)                                                            \
  {                                                                         \
    f32x16 sa = {}, sb = {};                                                \
    __builtin_amdgcn_s_setprio(1);                                          \
    sa = mfma32(kf##S[0], qf[0], sa);                                       \
    sb = mfma32(kf##S[1], qf[1], sb);                                       \
    sa = mfma32(kf##S[2], qf[2], sa);                                       \
    sb = mfma32(kf##S[3], qf[3], sb);                                       \
    __builtin_amdgcn_s_setprio(0);                                          \
    float p[16];                                                            \
    _Pragma("unroll")                                                       \
    for (int r = 0; r < 16; ++r) {                                          \
      p[r] = __builtin_amdgcn_exp2f((sa[r] + sb[r]) * C2 - ksq##S[r >> 2][r & 3]);  \
      dsum4[r & 3] += p[r];                                                 \
    }                                                                       \
    unsigned w[4][2];                                                       \
    _Pragma("unroll")                                                       \
    for (int m = 0; m < 4; ++m) {                                           \
      asm("v_cvt_pk_bf16_f32 %0, %1, %2" : "=v"(w[m][0]) : "v"(p[4 * m]), "v"(p[4 * m + 1]));     \
      asm("v_cvt_pk_bf16_f32 %0, %1, %2" : "=v"(w[m][1]) : "v"(p[4 * m + 2]), "v"(p[4 * m + 3])); \
    }                                                                       \
    __builtin_amdgcn_s_setprio(1);                                          \
    _Pragma("unroll")                                                       \
    for (int sj = 0; sj < 2; ++sj) {                                        \
      unsigned a0 = w[2 * sj][0], b0 = w[2 * sj + 1][0];                    \
      unsigned a1 = w[2 * sj][1], b1 = w[2 * sj + 1][1];                    \
      asm("v_permlane32_swap_b32 %0, %1" : "+v"(a0), "+v"(b0));             \
      asm("v_permlane32_swap_b32 %0, %1" : "+v"(a1), "+v"(b1));             \
      u32x4 pw; pw[0] = a0; pw[1] = a1; pw[2] = b0; pw[3] = b1;             \
      bf16x8 pa = __builtin_bit_cast(bf16x8, pw);                           \
      oacc[0] = mfma32(pa, vf##S[0][sj], oacc[0]);                          \
      oacc[1] = mfma32(pa, vf##S[1][sj], oacc[1]);                          \
    }                                                                       \
    __builtin_amdgcn_s_setprio(0);                                          \
  }

  int jb = jg * 16;
  LOADT(A, jb)
#pragma unroll 1
  for (int s = 0; s < 7; ++s) {
    LOADT(B, jb + 2 * s + 1)
    COMPT(A)
    LOADT(A, jb + 2 * s + 2)
    COMPT(B)
  }
  LOADT(B, jb + 15)
  COMPT(A)
  COMPT(B)

  float dsum = (dsum4[0] + dsum4[1]) + (dsum4[2] + dsum4[3]);
  dsum += __shfl_xor(dsum, 32);

  if (jg == 1) {
#pragma unroll
    for (int dh = 0; dh < 2; ++dh)
#pragma unroll
      for (int r = 0; r < 16; ++r)
        ob_l[dh * 16 + r][wq][lane] = oacc[dh][r];
    if (hi == 0) dsb[wq][l31] = dsum;
  }
  __syncthreads();
  if (jg == 0) {
#pragma unroll
    for (int dh = 0; dh < 2; ++dh)
#pragma unroll
      for (int r = 0; r < 16; ++r)
        oacc[dh][r] += ob_l[dh * 16 + r][wq][lane];
    dsum += dsb[wq][l31] + p0_l[wq * 32 + l31];
    float rden = 1.0f / dsum;
    if (hi == 0) dn_l[wq][l31] = rden;
  }
  __syncthreads();

  if (jg == 0) {
#pragma unroll
    for (int dh = 0; dh < 2; ++dh)
#pragma unroll
      for (int r = 0; r < 16; ++r) {
        int row = (r & 3) + 8 * (r >> 2) + 4 * hi;
        float o = oacc[dh][r] * dn_l[wq][row];
        att[((size_t)(b * 1024 + n0 + wq * 32 + row)) * 512 + h * 64 + dh * 32 + l31] = f2bf(o);
      }
  }
}

extern "C" void kernel_launch(void* const* d_in, const int* in_sizes, int n_in,
                              void* d_out, int out_size, void* d_ws, size_t ws_size,
                              hipStream_t stream) {
  const float* fmap = (const float*)d_in[0];
  const float* gamma = (const float*)d_in[1];
  const float* wq = (const float*)d_in[2];
  const float* wv = (const float*)d_in[3];
  const float* nkv = (const float*)d_in[4];
  const float* wo = (const float*)d_in[5];
  float* out = (float*)d_out;

  const size_t M4 = (size_t)8192 * 512;
  unsigned short* x_t = (unsigned short*)d_ws;        // [8192][512]
  unsigned short* QF  = x_t + M4;                     // q/k fragments
  unsigned short* VF  = QF + M4;                      // v fragments
  unsigned short* att = VF + M4;                      // [8192][512]
  unsigned short* wqb = att + M4;                     // [512][512]
  unsigned short* wvb = wqb + (size_t)512 * 512;
  unsigned short* wob = wvb + (size_t)512 * 512;
  float* qsqs = (float*)(wob + (size_t)512 * 512);    // [64][1024] scaled by COEF
  float* p0g  = qsqs + 65536;                         // [64][1024]

  prep_k<<<352, 256, 0, stream>>>(fmap, gamma, wq, wv, wo, x_t, wqb, wvb, wob);
  gemm_qv_k<<<dim3(4, 64), 512, 0, stream>>>(x_t, wqb, wvb, nkv, QF, VF, qsqs, p0g);
  attn_k<<<512, 512, 0, stream>>>(QF, VF, qsqs, p0g, nkv, att);
  gemm_o_k<<<512, 256, 0, stream>>>(wob, att, out);
}

// Round 13
// 66.063 us; speedup vs baseline: 3.9507x; 3.9507x over previous
//
#include <hip/hip_runtime.h>
#include <hip/hip_bf16.h>

#define DEV static __device__ __forceinline__

typedef __bf16 bf16x8 __attribute__((ext_vector_type(8)));
typedef float f32x4 __attribute__((ext_vector_type(4)));
typedef float f32x16 __attribute__((ext_vector_type(16)));
typedef unsigned u32x4 __attribute__((ext_vector_type(4)));
typedef unsigned short u16x8 __attribute__((ext_vector_type(8)));
typedef unsigned short u16x4 __attribute__((ext_vector_type(4)));

DEV unsigned short f2bf(float f) {
  unsigned u = __builtin_bit_cast(unsigned, f);
  u += 0x7fffu + ((u >> 16) & 1u);
  return (unsigned short)(u >> 16);
}
DEV float bf2f(unsigned short s) {
  return __builtin_bit_cast(float, (unsigned)s << 16);
}
DEV f32x4 mfma16(bf16x8 a, bf16x8 b, f32x4 c) {
  return __builtin_amdgcn_mfma_f32_16x16x32_bf16(a, b, c, 0, 0, 0);
}
DEV f32x16 mfma32(bf16x8 a, bf16x8 b, f32x16 c) {
  return __builtin_amdgcn_mfma_f32_32x32x16_bf16(a, b, c, 0, 0, 0);
}
DEV bf16x8 ld8(const unsigned short* p) {
  return __builtin_bit_cast(bf16x8, *(const u16x8*)p);
}
// async global->LDS, 16B per lane; LDS dest wave-uniform base + lane*16
DEV void gload16(const unsigned short* g, unsigned short* l) {
  auto* g1 = reinterpret_cast<const __attribute__((address_space(1))) unsigned int*>(
      reinterpret_cast<uintptr_t>(g));
  auto* l3 = reinterpret_cast<__attribute__((address_space(3))) unsigned int*>(
      reinterpret_cast<uintptr_t>(l));
  __builtin_amdgcn_global_load_lds(g1, l3, 16, 0, 0);
}

// ---------------- fused prep, single fmap pass, float4 global reads ----------------
__global__ __launch_bounds__(256) void prep_k(const float* __restrict__ fmap,
                                              const float* __restrict__ gamma,
                                              const float* __restrict__ wq,
                                              const float* __restrict__ wv,
                                              const float* __restrict__ wo,
                                              unsigned short* __restrict__ xt,
                                              unsigned short* __restrict__ wqb,
                                              unsigned short* __restrict__ wvb,
                                              unsigned short* __restrict__ wob) {
  int bid = blockIdx.x, tid = threadIdx.x;
  if (bid >= 256) {
    int t4 = bid - 256;            // 0..95, 32 blocks per tensor
    int g = t4 >> 5;
    const float* src = (g == 0) ? wq : (g == 1) ? wv : wo;
    unsigned short* dst = (g == 0) ? wqb : (g == 1) ? wvb : wob;
    int base = (t4 & 31) * 1024 + tid;
    const float4* s = (const float4*)src;
#pragma unroll
    for (int i = 0; i < 4; ++i) {
      int idx = base + i * 256;
      float4 a = s[idx * 2], b = s[idx * 2 + 1];
      u16x8 o;
      o[0] = f2bf(a.x); o[1] = f2bf(a.y); o[2] = f2bf(a.z); o[3] = f2bf(a.w);
      o[4] = f2bf(b.x); o[5] = f2bf(b.y); o[6] = f2bf(b.z); o[7] = f2bf(b.w);
      ((u16x8*)dst)[idx] = o;
    }
    return;
  }
  __shared__ float slab[512][33];   // [c][n_local], +1 pad
  __shared__ float psum[32][33];    // [cg][n] partial sums, +1 pad
  __shared__ float rn_l[32];
  __shared__ float gl[512];
  int b = bid >> 5, n0 = (bid & 31) * 32;
  gl[tid] = gamma[tid];
  gl[tid + 256] = gamma[tid + 256];
  // phase 1: float4 loads along n; 16 channels per thread
  int q = tid & 7, cg = tid >> 3;
  int n4 = q * 4;
  float s0 = 0.f, s1 = 0.f, s2 = 0.f, s3 = 0.f;
  const float* pb = fmap + ((size_t)(b * 512 + cg * 16)) * 1024 + n0 + n4;
#pragma unroll
  for (int i = 0; i < 16; ++i) {
    float4 v = *(const float4*)(pb + (size_t)i * 1024);
    int c = cg * 16 + i;
    slab[c][n4] = v.x; slab[c][n4 + 1] = v.y; slab[c][n4 + 2] = v.z; slab[c][n4 + 3] = v.w;
    s0 += v.x * v.x; s1 += v.y * v.y; s2 += v.z * v.z; s3 += v.w * v.w;
  }
  psum[cg][n4] = s0; psum[cg][n4 + 1] = s1; psum[cg][n4 + 2] = s2; psum[cg][n4 + 3] = s3;
  __syncthreads();
  if (tid < 32) {
    float ts = 0.f;
#pragma unroll
    for (int k = 0; k < 32; ++k) ts += psum[k][tid];
    rn_l[tid] = 22.62741699796952f / fmaxf(sqrtf(ts), 1e-12f);
  }
  __syncthreads();
  // phase 2: normalize + transpose from LDS, 16B stores
  int nn = tid >> 3, cc = tid & 7;
  float sc = rn_l[nn];
#pragma unroll
  for (int c0 = 0; c0 < 512; c0 += 64) {
    u16x8 o;
#pragma unroll
    for (int e = 0; e < 8; ++e) {
      int c = c0 + cc * 8 + e;
      o[e] = f2bf(slab[c][nn] * sc * gl[c]);
    }
    *(u16x8*)(xt + ((size_t)(b * 1024 + n0 + nn)) * 512 + c0 + cc * 8) = o;
  }
}

// ---------------- fused q+v GEMM, double-buffered 2-phase prefetch ------------------
__global__ __launch_bounds__(512) void gemm_qv_k(const unsigned short* __restrict__ A,
                                                 const unsigned short* __restrict__ wqb,
                                                 const unsigned short* __restrict__ wvb,
                                                 const float* __restrict__ nkv,
                                                 unsigned short* __restrict__ QF,
                                                 unsigned short* __restrict__ VF,
                                                 float* __restrict__ qsqs,
                                                 float* __restrict__ p0g) {
  __shared__ unsigned short a_lds[2][128 * 64];
  __shared__ unsigned short bq_lds[2][128 * 64];
  __shared__ unsigned short bv_lds[2][128 * 64];   // 96 KB total
  int tid = threadIdx.x, lane = tid & 63, wid = tid >> 6;
  int isV = wid >> 2, gw = wid & 3;
  int wr = gw >> 1, wc = gw & 1;
  int m0 = blockIdx.y * 128, n0 = blockIdx.x * 128;
  int srow = (lane >> 3);
  int scol = ((lane & 7) ^ ((lane >> 3) & 7)) * 8;
  f32x4 acc[4][4] = {};

#define QV_STAGE(BUF, KT)                                                          \
  {                                                                                \
    int il0 = wid * 2;                                                             \
    _Pragma("unroll")                                                              \
    for (int i = 0; i < 2; ++i) {                                                  \
      int il = il0 + i;                                                            \
      gload16(A + (size_t)(m0 + il * 8 + srow) * 512 + (KT) + scol, &a_lds[BUF][il * 512]);   \
      gload16(wqb + (size_t)(n0 + il * 8 + srow) * 512 + (KT) + scol, &bq_lds[BUF][il * 512]); \
      gload16(wvb + (size_t)(n0 + il * 8 + srow) * 512 + (KT) + scol, &bv_lds[BUF][il * 512]); \
    }                                                                              \
  }

  QV_STAGE(0, 0)
  asm volatile("s_waitcnt vmcnt(0)" ::: "memory");
  __syncthreads();
  int cur = 0;
#pragma unroll 1
  for (int t = 0; t < 8; ++t) {
    if (t < 7) QV_STAGE(cur ^ 1, (t + 1) * 64)
    const unsigned short* al = &a_lds[cur][0];
    const unsigned short* bl = isV ? &bv_lds[cur][0] : &bq_lds[cur][0];
#pragma unroll
    for (int ks = 0; ks < 2; ++ks) {
      int c = ks * 4 + (lane >> 4);
      int cs = (c ^ (lane & 7)) * 8;
      bf16x8 af[4], bfr[4];
#pragma unroll
      for (int rt = 0; rt < 4; ++rt)
        af[rt] = ld8(&al[(wr * 64 + rt * 16 + (lane & 15)) * 64 + cs]);
#pragma unroll
      for (int ct = 0; ct < 4; ++ct)
        bfr[ct] = ld8(&bl[(wc * 64 + ct * 16 + (lane & 15)) * 64 + cs]);
#pragma unroll
      for (int rt = 0; rt < 4; ++rt)
#pragma unroll
        for (int ct = 0; ct < 4; ++ct)
          acc[rt][ct] = mfma16(af[rt], bfr[ct], acc[rt][ct]);
    }
    asm volatile("s_waitcnt vmcnt(0)" ::: "memory");
    __syncthreads();
    cur ^= 1;
  }
  if (!isV) {
    const float COEF = 0.18033688011112042f;  // 0.125 * log2(e)
    int head = blockIdx.x * 2 + wc;
    const float* nk = nkv + head * 64;
    float nk_own[4], nks = 0.f;
#pragma unroll
    for (int ct = 0; ct < 4; ++ct) {
      nk_own[ct] = nk[ct * 16 + (lane & 15)];
      nks += nk_own[ct] * nk_own[ct];
    }
    nks += __shfl_xor(nks, 1); nks += __shfl_xor(nks, 2);
    nks += __shfl_xor(nks, 4); nks += __shfl_xor(nks, 8);
#pragma unroll
    for (int rt = 0; rt < 4; ++rt)
#pragma unroll
      for (int r = 0; r < 4; ++r) {
        float qs = 0.f, dot = 0.f;
        unsigned short qr[4];
#pragma unroll
        for (int ct = 0; ct < 4; ++ct) {
          unsigned short us = f2bf(acc[rt][ct][r]);
          qr[ct] = us;
          float v = bf2f(us);
          qs += v * v;
          dot += v * nk_own[ct];
        }
        int n = m0 + wr * 64 + rt * 16 + (lane >> 4) * 4 + r;
        int bb = n >> 10, nl = n & 1023;
        int bh = bb * 8 + head;
        size_t fidx = (size_t)(bh * 32 + (nl >> 5)) * 2048 + (nl & 31) * 16 + (lane & 15);
#pragma unroll
        for (int ct = 0; ct < 4; ++ct) QF[fidx + ct * 512] = qr[ct];
        qs += __shfl_xor(qs, 1); qs += __shfl_xor(qs, 2);
        qs += __shfl_xor(qs, 4); qs += __shfl_xor(qs, 8);
        dot += __shfl_xor(dot, 1); dot += __shfl_xor(dot, 2);
        dot += __shfl_xor(dot, 4); dot += __shfl_xor(dot, 8);
        if ((lane & 15) == 0) {
          qsqs[bh * 1024 + nl] = qs * COEF;
          p0g[bh * 1024 + nl] = __builtin_amdgcn_exp2f((2.f * dot - nks) * COEF);
        }
      }
  } else {
#pragma unroll
    for (int rt = 0; rt < 4; ++rt)
#pragma unroll
      for (int ct = 0; ct < 4; ++ct) {
        int nb = m0 + wr * 64 + rt * 16 + (lane >> 4) * 4;
        int o = n0 + wc * 64 + ct * 16 + (lane & 15);
        int b = nb >> 10, j = nb & 1023;
        int h = o >> 6, d = o & 63;
        int bh = b * 8 + h;
        size_t idx = (size_t)(bh * 32 + (j >> 5)) * 2048 + ((j >> 4) & 1) * 1024 + (d >> 5) * 512 +
                     (d & 31) * 16 + (j & 15);
        u16x4 pk;
#pragma unroll
        for (int r = 0; r < 4; ++r) pk[r] = f2bf(acc[rt][ct][r]);
        *(u16x4*)(VF + idx) = pk;
      }
  }
}

// ---------------- out-projection GEMM: 64x128x512, dbuf 2-phase prefetch ------------
__global__ __launch_bounds__(256) void gemm_o_k(const unsigned short* __restrict__ A,
                                                const unsigned short* __restrict__ Bt,
                                                float* __restrict__ Cp) {
  __shared__ unsigned short a_lds[2][64 * 64];
  __shared__ unsigned short b_lds[2][128 * 64];   // 48 KB
  int bid = blockIdx.x;
  int y = (bid >> 3) & 7;
  int x = (bid & 7) + ((bid >> 6) << 3);
  int m0 = y * 64, n0 = x * 128;
  int tid = threadIdx.x, lane = tid & 63, wid = tid >> 6;
  int wr = wid >> 1, wc = wid & 1;
  int srow = (lane >> 3);
  int scol = ((lane & 7) ^ ((lane >> 3) & 7)) * 8;
  f32x4 acc[2][4] = {};

#define O_STAGE(BUF, KT)                                                           \
  {                                                                                \
    _Pragma("unroll")                                                              \
    for (int i = 0; i < 2; ++i) {                                                  \
      int il = wid * 2 + i;                                                        \
      gload16(A + (size_t)(m0 + il * 8 + srow) * 512 + (KT) + scol, &a_lds[BUF][il * 512]);    \
    }                                                                              \
    _Pragma("unroll")                                                              \
    for (int i = 0; i < 4; ++i) {                                                  \
      int il = wid * 4 + i;                                                        \
      gload16(Bt + (size_t)(n0 + il * 8 + srow) * 512 + (KT) + scol, &b_lds[BUF][il * 512]);   \
    }                                                                              \
  }

  O_STAGE(0, 0)
  asm volatile("s_waitcnt vmcnt(0)" ::: "memory");
  __syncthreads();
  int cur = 0;
#pragma unroll 1
  for (int t = 0; t < 8; ++t) {
    if (t < 7) O_STAGE(cur ^ 1, (t + 1) * 64)
    const unsigned short* al = &a_lds[cur][0];
    const unsigned short* bl = &b_lds[cur][0];
#pragma unroll
    for (int ks = 0; ks < 2; ++ks) {
      int c = ks * 4 + (lane >> 4);
      int cs = (c ^ (lane & 7)) * 8;
      bf16x8 af[2], bfr[4];
#pragma unroll
      for (int rt = 0; rt < 2; ++rt)
        af[rt] = ld8(&al[(wr * 32 + rt * 16 + (lane & 15)) * 64 + cs]);
#pragma unroll
      for (int ct = 0; ct < 4; ++ct)
        bfr[ct] = ld8(&bl[(wc * 64 + ct * 16 + (lane & 15)) * 64 + cs]);
#pragma unroll
      for (int rt = 0; rt < 2; ++rt)
#pragma unroll
        for (int ct = 0; ct < 4; ++ct)
          acc[rt][ct] = mfma16(af[rt], bfr[ct], acc[rt][ct]);
    }
    asm volatile("s_waitcnt vmcnt(0)" ::: "memory");
    __syncthreads();
    cur ^= 1;
  }
  int bb = n0 >> 10;
#pragma unroll
  for (int rt = 0; rt < 2; ++rt)
#pragma unroll
    for (int ct = 0; ct < 4; ++ct)
#pragma unroll
      for (int r = 0; r < 4; ++r) {
        int row = m0 + wr * 32 + rt * 16 + (lane >> 4) * 4 + r;        // c
        int col = (n0 & 1023) + wc * 64 + ct * 16 + (lane & 15);       // n
        Cp[((size_t)(bb * 512 + row)) * 1024 + col] = acc[rt][ct][r];
      }
}

// ---------------- fused distance-attention, j-split, split QK chains ----------------
__global__ __launch_bounds__(512) void attn_k(const unsigned short* __restrict__ QF,
                                              const unsigned short* __restrict__ VF,
                                              const float* __restrict__ qsqs,
                                              const float* __restrict__ p0g,
                                              const float* __restrict__ nkv,
                                              unsigned short* __restrict__ att) {
  const float C2 = 0.36067376022224085f;  // 0.25 * log2(e)
  int bid = blockIdx.x;
  int s0 = bid >> 3;
  int bh = ((bid & 7) << 3) | (s0 & 7);
  int qt = s0 >> 3;
  int b = bh >> 3, h = bh & 7;
  int n0 = qt * 128;
  int tid = threadIdx.x, lane = tid & 63, wid = tid >> 6;
  int wq = wid & 3, jg = wid >> 2;
  int l31 = lane & 31, hi = lane >> 5;

  __shared__ float ob_l[32][4][64];
  __shared__ float dsb[4][32];
  __shared__ float p0_l[128];
  __shared__ float nv_l[64];
  __shared__ float dn_l[4][32];

  if (tid < 128) p0_l[tid] = p0g[bh * 1024 + n0 + tid];
  else if (tid < 192) nv_l[tid - 128] = nkv[512 + h * 64 + (tid - 128)];
  __syncthreads();

  bf16x8 qf[4];
  const unsigned short* qfp = QF + (size_t)(bh * 32 + qt * 4 + wq) * 2048 + l31 * 16 + hi * 8;
#pragma unroll
  for (int ks = 0; ks < 4; ++ks)
    qf[ks] = ld8(qfp + ks * 512);

  f32x16 oacc[2];
#pragma unroll
  for (int dh = 0; dh < 2; ++dh)
#pragma unroll
    for (int r = 0; r < 16; ++r) {
      int row = (r & 3) + 8 * (r >> 2) + 4 * hi;
      oacc[dh][r] = (jg == 0) ? p0_l[wq * 32 + row] * nv_l[dh * 32 + l31] : 0.f;
    }

  f32x4 dsum4 = {0.f, 0.f, 0.f, 0.f};
  const unsigned short* kbase = QF + (size_t)bh * 65536 + l31 * 16 + hi * 8;
  const unsigned short* vbase = VF + (size_t)bh * 65536 + l31 * 16 + hi * 8;
  const float* ksb = qsqs + bh * 1024 + 4 * hi;

  bf16x8 kfA[4], kfB[4], vfA[2][2], vfB[2][2];
  f32x4 ksqA[4], ksqB[4];

#define LOADT(S, JT)                                                        \
  {                                                                         \
    const unsigned short* kp_ = kbase + (JT) * 2048;                        \
    kf##S[0] = ld8(kp_);        kf##S[1] = ld8(kp_ + 512);                  \
    kf##S[2] = ld8(kp_ + 1024); kf##S[3] = ld8(kp_ + 1536);                 \
    const unsigned short* vp_ = vbase + (JT) * 2048;                        \
    vf##S[0][0] = ld8(vp_);        vf##S[0][1] = ld8(vp_ + 1024);           \
    vf##S[1][0] = ld8(vp_ + 512);  vf##S[1][1] = ld8(vp_ + 1536);           \
    const float* kq_ = ksb + (JT) * 32;                                     \
    ksq##S[0] = *(const f32x4*)(kq_);      ksq##S[1] = *(const f32x4*)(kq_ + 8);  \
    ksq##S[2] = *(const f32x4*)(kq_ + 16); ksq##S[3] = *(const f32x4*)(kq_ + 24); \
  }

#define COMPT(S)                                                            \
  {                                                                         \
    f32x16 sa = {}, sb = {};                                                \
    __builtin_amdgcn_s_setprio(1);                                          \
    sa = mfma32(kf##S[0], qf[0], sa);                                       \
    sb = mfma32(kf##S[1], qf[1], sb);                                       \
    sa = mfma32(kf##S[2], qf[2], sa);                                       \
    sb = mfma32(kf##S[3], qf[3], sb);                                       \
    __builtin_amdgcn_s_setprio(0);                                          \
    float p[16];                                                            \
    _Pragma("unroll")                                                       \
    for (int r = 0; r < 16; ++r) {                                          \
      p[r] = __builtin_amdgcn_exp2f((sa[r] + sb[r]) * C2 - ksq##S[r >> 2][r & 3]);  \
      dsum4[r & 3] += p[r];                                                 \
    }                                                                       \
    unsigned w[4][2];                                                       \
    _Pragma("unroll")                                                       \
    for (int m = 0; m < 4; ++m) {                                           \
      asm("v_cvt_pk_bf16_f32 %0, %1, %2" : "=v"(w[m][0]) : "v"(p[4 * m]), "v"(p[4 * m + 1]));     \
      asm("v_cvt_pk_bf16_f32 %0, %1, %2" : "=v"(w[m][1]) : "v"(p[4 * m + 2]), "v"(p[4 * m + 3])); \
    }                                                                       \
    __builtin_amdgcn_s_setprio(1);                                          \
    _Pragma("unroll")                                                       \
    for (int sj = 0; sj < 2; ++sj) {                                        \
      unsigned a0 = w[2 * sj][0], b0 = w[2 * sj + 1][0];                    \
      unsigned a1 = w[2 * sj][1], b1 = w[2 * sj + 1][1];                    \
      asm("v_permlane32_swap_b32 %0, %1" : "+v"(a0), "+v"(b0));             \
      asm("v_permlane32_swap_b32 %0, %1" : "+v"(a1), "+v"(b1));             \
      u32x4 pw; pw[0] = a0; pw[1] = a1; pw[2] = b0; pw[3] = b1;             \
      bf16x8 pa = __builtin_bit_cast(bf16x8, pw);                           \
      oacc[0] = mfma32(pa, vf##S[0][sj], oacc[0]);                          \
      oacc[1] = mfma32(pa, vf##S[1][sj], oacc[1]);                          \
    }                                                                       \
    __builtin_amdgcn_s_setprio(0);                                          \
  }

  int jb = jg * 16;
  LOADT(A, jb)
#pragma unroll 1
  for (int s = 0; s < 7; ++s) {
    LOADT(B, jb + 2 * s + 1)
    COMPT(A)
    LOADT(A, jb + 2 * s + 2)
    COMPT(B)
  }
  LOADT(B, jb + 15)
  COMPT(A)
  COMPT(B)

  float dsum = (dsum4[0] + dsum4[1]) + (dsum4[2] + dsum4[3]);
  dsum += __shfl_xor(dsum, 32);

  if (jg == 1) {
#pragma unroll
    for (int dh = 0; dh < 2; ++dh)
#pragma unroll
      for (int r = 0; r < 16; ++r)
        ob_l[dh * 16 + r][wq][lane] = oacc[dh][r];
    if (hi == 0) dsb[wq][l31] = dsum;
  }
  __syncthreads();
  if (jg == 0) {
#pragma unroll
    for (int dh = 0; dh < 2; ++dh)
#pragma unroll
      for (int r = 0; r < 16; ++r)
        oacc[dh][r] += ob_l[dh * 16 + r][wq][lane];
    dsum += dsb[wq][l31] + p0_l[wq * 32 + l31];
    float rden = 1.0f / dsum;
    if (hi == 0) dn_l[wq][l31] = rden;
  }
  __syncthreads();

  if (jg == 0) {
#pragma unroll
    for (int dh = 0; dh < 2; ++dh)
#pragma unroll
      for (int r = 0; r < 16; ++r) {
        int row = (r & 3) + 8 * (r >> 2) + 4 * hi;
        float o = oacc[dh][r] * dn_l[wq][row];
        att[((size_t)(b * 1024 + n0 + wq * 32 + row)) * 512 + h * 64 + dh * 32 + l31] = f2bf(o);
      }
  }
}

extern "C" void kernel_launch(void* const* d_in, const int* in_sizes, int n_in,
                              void* d_out, int out_size, void* d_ws, size_t ws_size,
                              hipStream_t stream) {
  const float* fmap = (const float*)d_in[0];
  const float* gamma = (const float*)d_in[1];
  const float* wq = (const float*)d_in[2];
  const float* wv = (const float*)d_in[3];
  const float* nkv = (const float*)d_in[4];
  const float* wo = (const float*)d_in[5];
  float* out = (float*)d_out;

  const size_t M4 = (size_t)8192 * 512;
  unsigned short* x_t = (unsigned short*)d_ws;        // [8192][512]
  unsigned short* QF  = x_t + M4;                     // q/k fragments
  unsigned short* VF  = QF + M4;                      // v fragments
  unsigned short* att = VF + M4;                      // [8192][512]
  unsigned short* wqb = att + M4;                     // [512][512]
  unsigned short* wvb = wqb + (size_t)512 * 512;
  unsigned short* wob = wvb + (size_t)512 * 512;
  float* qsqs = (float*)(wob + (size_t)512 * 512);    // [64][1024] scaled by COEF
  float* p0g  = qsqs + 65536;                         // [64][1024]

  prep_k<<<352, 256, 0, stream>>>(fmap, gamma, wq, wv, wo, x_t, wqb, wvb, wob);
  gemm_qv_k<<<dim3(4, 64), 512, 0, stream>>>(x_t, wqb, wvb, nkv, QF, VF, qsqs, p0g);
  attn_k<<<512, 512, 0, stream>>>(QF, VF, qsqs, p0g, nkv, att);
  gemm_o_k<<<512, 256, 0, stream>>>(wob, att, out);
}